// Round 1
// baseline (215.098 us; speedup 1.0000x reference)
//
#include <hip/hip_runtime.h>
#include <math.h>

#define FF 6
#define HH 32

__device__ __forceinline__ float sigmoidf_(float x) {
    return 1.0f / (1.0f + __expf(-x));
}

// Precompute folded edge-predictor weights into ws (512 floats):
// rec[h*16 + m]      (m<6)  = A[m][h]  = sum_k Wn[m][k]*We1[k][h]
// rec[h*16 + 6 + m]  (m<6)  = Bm[m][h] = sum_k Wn[m][k]*We1[32+k][h]
// rec[h*16 + 12]            = c0[h]    = sum_k bn[k]*(We1[k][h]+We1[32+k][h]) + be1[h]
// rec[h*16 + 13]            = We2[h]
__global__ void fold_kernel(const float* __restrict__ Wn,
                            const float* __restrict__ bn,
                            const float* __restrict__ We1,
                            const float* __restrict__ be1,
                            const float* __restrict__ We2,
                            float* __restrict__ rec) {
    int t = threadIdx.x;          // 512 threads, one block
    int h = t >> 4, s = t & 15;
    float val = 0.0f;
    if (s < 6) {
        #pragma unroll
        for (int k = 0; k < 32; ++k) val = fmaf(Wn[s*32+k], We1[k*32+h], val);
    } else if (s < 12) {
        int m = s - 6;
        #pragma unroll
        for (int k = 0; k < 32; ++k) val = fmaf(Wn[m*32+k], We1[(32+k)*32+h], val);
    } else if (s == 12) {
        #pragma unroll
        for (int k = 0; k < 32; ++k) val = fmaf(bn[k], We1[k*32+h] + We1[(32+k)*32+h], val);
        val += be1[h];
    } else if (s == 13) {
        val = We2[h];
    }
    rec[t] = val;
}

// One thread per (sample b, row i): computes adj[b][i][0..5], zeroes scores[b].
__global__ __launch_bounds__(256) void adj_kernel(const float* __restrict__ factors,
                                                  const float* __restrict__ rec,
                                                  const float* __restrict__ be2,
                                                  float* __restrict__ adj_out,
                                                  float* __restrict__ scores,
                                                  int B) {
    int t = blockIdx.x * 256 + threadIdx.x;
    int b = t / 6;
    int i = t - b * 6;
    if (b >= B) return;
    if (i == 0) scores[b] = 0.0f;   // dyn_kernel (later launch) accumulates into this

    const float* f = factors + (size_t)b * 36;
    float fall[36];
    #pragma unroll
    for (int q = 0; q < 9; ++q) {
        float4 v = reinterpret_cast<const float4*>(f)[q];
        fall[q*4+0] = v.x; fall[q*4+1] = v.y; fall[q*4+2] = v.z; fall[q*4+3] = v.w;
    }
    float fi[6];
    #pragma unroll
    for (int m = 0; m < 6; ++m) fi[m] = f[i*6 + m];

    float acc[6];
    #pragma unroll
    for (int j = 0; j < 6; ++j) acc[j] = 0.0f;

    #pragma unroll
    for (int h = 0; h < 32; ++h) {
        const float* r = rec + h * 16;   // uniform address -> scalar loads
        float uh = r[12];
        #pragma unroll
        for (int m = 0; m < 6; ++m) uh = fmaf(fi[m], r[m], uh);
        float w2 = r[13];
        #pragma unroll
        for (int j = 0; j < 6; ++j) {
            float vj = 0.0f;
            #pragma unroll
            for (int m = 0; m < 6; ++m) vj = fmaf(fall[j*6 + m], r[6 + m], vj);
            float e = uh + vj;
            e = e > 0.0f ? e : 0.0f;
            acc[j] = fmaf(e, w2, acc[j]);
        }
    }

    float b2 = be2[0];
    float* o = adj_out + (size_t)b * 36 + i * 6;
    #pragma unroll
    for (int j = 0; j < 6; ++j) {
        o[j] = (j == i) ? 0.0f : sigmoidf_(acc[j] + b2);
    }
}

// One thread per (sample b, node n): structured -> dynamics -> pred -> scorer.
__global__ __launch_bounds__(256) void dyn_kernel(const float* __restrict__ factors,
                                                  const float* __restrict__ adj,
                                                  const float* __restrict__ Wd1, const float* __restrict__ bd1,
                                                  const float* __restrict__ Wd2, const float* __restrict__ bd2,
                                                  const float* __restrict__ Wd3, const float* __restrict__ bd3,
                                                  const float* __restrict__ Ws1, const float* __restrict__ bs1,
                                                  const float* __restrict__ Ws2, const float* __restrict__ bs2,
                                                  const float* __restrict__ Ws3, const float* __restrict__ bs3,
                                                  float* __restrict__ pred_out,
                                                  float* __restrict__ scores,
                                                  int B) {
    int t = blockIdx.x * 256 + threadIdx.x;
    int b = t / 6;
    int n = t - b * 6;
    if (b >= B) return;

    float fn[6];
    #pragma unroll
    for (int m = 0; m < 6; ++m) fn[m] = factors[(size_t)b*36 + n*6 + m];

    float adjv[36];
    const float* ap = adj + (size_t)b * 36;
    #pragma unroll
    for (int q = 0; q < 9; ++q) {
        float4 v = reinterpret_cast<const float4*>(ap)[q];
        adjv[q*4+0] = v.x; adjv[q*4+1] = v.y; adjv[q*4+2] = v.z; adjv[q*4+3] = v.w;
    }

    // structured[n][i] = sum_j adj[i][j] * f[n][j]
    float st[6];
    #pragma unroll
    for (int i = 0; i < 6; ++i) {
        float s = 0.0f;
        #pragma unroll
        for (int j = 0; j < 6; ++j) s = fmaf(adjv[i*6 + j], fn[j], s);
        st[i] = s;
    }

    // h1 = relu(st @ Wd1 + bd1)
    float h1[32];
    #pragma unroll
    for (int o = 0; o < 32; ++o) h1[o] = bd1[o];
    #pragma unroll
    for (int m = 0; m < 6; ++m) {
        float sm = st[m];
        #pragma unroll
        for (int o = 0; o < 32; ++o) h1[o] = fmaf(sm, Wd1[m*32 + o], h1[o]);
    }
    #pragma unroll
    for (int o = 0; o < 32; ++o) h1[o] = fmaxf(h1[o], 0.0f);

    // h2 = relu(h1 @ Wd2 + bd2)
    float h2[32];
    #pragma unroll
    for (int o = 0; o < 32; ++o) h2[o] = bd2[o];
    #pragma unroll
    for (int k = 0; k < 32; ++k) {
        float hk = h1[k];
        #pragma unroll
        for (int o = 0; o < 32; ++o) h2[o] = fmaf(hk, Wd2[k*32 + o], h2[o]);
    }
    #pragma unroll
    for (int o = 0; o < 32; ++o) h2[o] = fmaxf(h2[o], 0.0f);

    // pred = h2 @ Wd3 + bd3
    float pr[6];
    #pragma unroll
    for (int j = 0; j < 6; ++j) pr[j] = bd3[j];
    #pragma unroll
    for (int k = 0; k < 32; ++k) {
        float hk = h2[k];
        #pragma unroll
        for (int j = 0; j < 6; ++j) pr[j] = fmaf(hk, Wd3[k*6 + j], pr[j]);
    }
    float* po = pred_out + (size_t)b * 36 + n * 6;
    #pragma unroll
    for (int j = 0; j < 6; ++j) po[j] = pr[j];

    float df[6];
    #pragma unroll
    for (int j = 0; j < 6; ++j) df[j] = fabsf(fn[j] - pr[j]);

    // s1 = relu(si @ Ws1 + bs1), si = [fn, pr, df] (18)
    float s1[32];
    #pragma unroll
    for (int o = 0; o < 32; ++o) s1[o] = bs1[o];
    #pragma unroll
    for (int m = 0; m < 6; ++m) {
        float a = fn[m], p = pr[m], d = df[m];
        #pragma unroll
        for (int o = 0; o < 32; ++o) s1[o] = fmaf(a, Ws1[m*32 + o], s1[o]);
        #pragma unroll
        for (int o = 0; o < 32; ++o) s1[o] = fmaf(p, Ws1[(6+m)*32 + o], s1[o]);
        #pragma unroll
        for (int o = 0; o < 32; ++o) s1[o] = fmaf(d, Ws1[(12+m)*32 + o], s1[o]);
    }
    #pragma unroll
    for (int o = 0; o < 32; ++o) s1[o] = fmaxf(s1[o], 0.0f);

    // s2 = relu(s1 @ Ws2 + bs2)
    float s2[16];
    #pragma unroll
    for (int o = 0; o < 16; ++o) s2[o] = bs2[o];
    #pragma unroll
    for (int k = 0; k < 32; ++k) {
        float sk = s1[k];
        #pragma unroll
        for (int o = 0; o < 16; ++o) s2[o] = fmaf(sk, Ws2[k*16 + o], s2[o]);
    }
    #pragma unroll
    for (int o = 0; o < 16; ++o) s2[o] = fmaxf(s2[o], 0.0f);

    // s3 = sigmoid(s2 @ Ws3 + bs3)
    float s3 = bs3[0];
    #pragma unroll
    for (int k = 0; k < 16; ++k) s3 = fmaf(s2[k], Ws3[k], s3);
    float sc = sigmoidf_(s3);

    atomicAdd(&scores[b], sc * (1.0f / 6.0f));
}

extern "C" void kernel_launch(void* const* d_in, const int* in_sizes, int n_in,
                              void* d_out, int out_size, void* d_ws, size_t ws_size,
                              hipStream_t stream) {
    const float* factors = (const float*)d_in[0];
    const float* Wn  = (const float*)d_in[1];
    const float* bn  = (const float*)d_in[2];
    const float* We1 = (const float*)d_in[3];
    const float* be1 = (const float*)d_in[4];
    const float* We2 = (const float*)d_in[5];
    const float* be2 = (const float*)d_in[6];
    const float* Wd1 = (const float*)d_in[7];
    const float* bd1 = (const float*)d_in[8];
    const float* Wd2 = (const float*)d_in[9];
    const float* bd2 = (const float*)d_in[10];
    const float* bd3 = (const float*)d_in[12];
    const float* Wd3 = (const float*)d_in[11];
    const float* Ws1 = (const float*)d_in[13];
    const float* bs1 = (const float*)d_in[14];
    const float* Ws2 = (const float*)d_in[15];
    const float* bs2 = (const float*)d_in[16];
    const float* Ws3 = (const float*)d_in[17];
    const float* bs3 = (const float*)d_in[18];

    int B = in_sizes[0] / 36;

    float* adj_out  = (float*)d_out;                       // [B,6,6]
    float* pred_out = (float*)d_out + (size_t)B * 36;      // [B,6,6]
    float* scores   = (float*)d_out + (size_t)B * 72;      // [B]
    float* rec      = (float*)d_ws;                        // 512 floats

    hipLaunchKernelGGL(fold_kernel, dim3(1), dim3(512), 0, stream,
                       Wn, bn, We1, be1, We2, rec);

    int nthreads = B * 6;
    int nblocks = (nthreads + 255) / 256;
    hipLaunchKernelGGL(adj_kernel, dim3(nblocks), dim3(256), 0, stream,
                       factors, rec, be2, adj_out, scores, B);

    hipLaunchKernelGGL(dyn_kernel, dim3(nblocks), dim3(256), 0, stream,
                       factors, adj_out,
                       Wd1, bd1, Wd2, bd2, Wd3, bd3,
                       Ws1, bs1, Ws2, bs2, Ws3, bs3,
                       pred_out, scores, B);
}

// Round 2
// 163.999 us; speedup vs baseline: 1.3116x; 1.3116x over previous
//
#include <hip/hip_runtime.h>
#include <math.h>

#define SPB 42          // samples per block (42*6 = 252 active threads of 256)
#define NT  256

__device__ __forceinline__ float sigmoidf_(float x) {
    return 1.0f / (1.0f + __expf(-x));
}

// Precompute folded edge-predictor weights into ws (512 floats):
// rec[h*16 + m]      (m<6)  = A[m][h]  = sum_k Wn[m][k]*We1[k][h]
// rec[h*16 + 6 + m]  (m<6)  = Bm[m][h] = sum_k Wn[m][k]*We1[32+k][h]
// rec[h*16 + 12]            = c0[h]    = sum_k bn[k]*(We1[k][h]+We1[32+k][h]) + be1[h]
// rec[h*16 + 13]            = We2[h]
__global__ void fold_kernel(const float* __restrict__ Wn,
                            const float* __restrict__ bn,
                            const float* __restrict__ We1,
                            const float* __restrict__ be1,
                            const float* __restrict__ We2,
                            float* __restrict__ rec) {
    int t = threadIdx.x;          // 512 threads, one block
    int h = t >> 4, s = t & 15;
    float val = 0.0f;
    if (s < 6) {
        #pragma unroll
        for (int k = 0; k < 32; ++k) val = fmaf(Wn[s*32+k], We1[k*32+h], val);
    } else if (s < 12) {
        int m = s - 6;
        #pragma unroll
        for (int k = 0; k < 32; ++k) val = fmaf(Wn[m*32+k], We1[(32+k)*32+h], val);
    } else if (s == 12) {
        #pragma unroll
        for (int k = 0; k < 32; ++k) val = fmaf(bn[k], We1[k*32+h] + We1[(32+k)*32+h], val);
        val += be1[h];
    } else if (s == 13) {
        val = We2[h];
    }
    rec[t] = val;
}

// ---- LDS float offsets (all multiples of 4 for float4 alignment) ----
#define O_REC  0      // 512
#define O_WD1  512    // 192  [m][o] 6x32
#define O_BD1  704    // 32
#define O_WD2  736    // 1024 [k][o] 32x32
#define O_BD2  1760   // 32
#define O_WD3  1792   // 192  [k][j] 32x6
#define O_BD3  1984   // 8 (6 used)
#define O_WS1  1992   // 576  [m][o] 18x32
#define O_BS1  2568   // 32
#define O_WS2  2600   // 512  [k][o] 32x16
#define O_BS2  3112   // 16
#define O_WS3  3128   // 16
#define O_MISC 3144   // [0]=bs3, [1]=be2
#define W_TOT  3148

__device__ __forceinline__ void cpy(float* dst, const float* src, int n, int t) {
    for (int i = t; i < n; i += NT) dst[i] = src[i];
}

__global__ __launch_bounds__(NT) void fused_kernel(
        const float* __restrict__ factors,
        const float* __restrict__ rec_g,
        const float* __restrict__ Wd1, const float* __restrict__ bd1,
        const float* __restrict__ Wd2, const float* __restrict__ bd2,
        const float* __restrict__ Wd3, const float* __restrict__ bd3,
        const float* __restrict__ Ws1, const float* __restrict__ bs1,
        const float* __restrict__ Ws2, const float* __restrict__ bs2,
        const float* __restrict__ Ws3, const float* __restrict__ bs3,
        const float* __restrict__ be2,
        float* __restrict__ adj_out,
        float* __restrict__ pred_out,
        float* __restrict__ scores,
        int B) {
    __shared__ float W[W_TOT];
    __shared__ float adj_s[SPB * 36];
    __shared__ float sc_s[SPB * 6];

    const int t = threadIdx.x;
    // ---- stage all weights into LDS (coalesced) ----
    cpy(W + O_REC, rec_g, 512, t);
    cpy(W + O_WD1, Wd1, 192, t);
    cpy(W + O_BD1, bd1, 32, t);
    cpy(W + O_WD2, Wd2, 1024, t);
    cpy(W + O_BD2, bd2, 32, t);
    cpy(W + O_WD3, Wd3, 192, t);
    if (t < 6)  W[O_BD3 + t] = bd3[t];
    cpy(W + O_WS1, Ws1, 576, t);
    cpy(W + O_BS1, bs1, 32, t);
    cpy(W + O_WS2, Ws2, 512, t);
    cpy(W + O_BS2, bs2, 16, t);
    cpy(W + O_WS3, Ws3, 16, t);
    if (t == 0) { W[O_MISC] = bs3[0]; W[O_MISC + 1] = be2[0]; }
    __syncthreads();

    const int s = t / 6;
    const int n = t - s * 6;
    const int b = blockIdx.x * SPB + s;
    const bool active = (t < SPB * 6) && (b < B);

    float fall[36], fi[6];

    if (active) {
        const float* f = factors + (size_t)b * 36;
        #pragma unroll
        for (int q = 0; q < 9; ++q) {
            float4 v = reinterpret_cast<const float4*>(f)[q];
            fall[q*4+0] = v.x; fall[q*4+1] = v.y; fall[q*4+2] = v.z; fall[q*4+3] = v.w;
        }
        #pragma unroll
        for (int m = 0; m < 6; ++m) fi[m] = f[n*6 + m];   // direct loads (avoid dyn reg-index)

        // ---- edge phase: acc[j] = sum_h relu(U[n][h]+V[j][h]+c0[h]) * w2[h] ----
        float acc[6] = {0.f, 0.f, 0.f, 0.f, 0.f, 0.f};
        for (int h = 0; h < 32; ++h) {
            const float* r = &W[O_REC + h * 16];
            float4 r0 = *reinterpret_cast<const float4*>(&r[0]);
            float4 r1 = *reinterpret_cast<const float4*>(&r[4]);
            float4 r2 = *reinterpret_cast<const float4*>(&r[8]);
            float4 r3 = *reinterpret_cast<const float4*>(&r[12]);
            float ra0 = r0.x, ra1 = r0.y, ra2 = r0.z, ra3 = r0.w, ra4 = r1.x, ra5 = r1.y;
            float rb0 = r1.z, rb1 = r1.w, rb2 = r2.x, rb3 = r2.y, rb4 = r2.z, rb5 = r2.w;
            float c0 = r3.x, w2 = r3.y;

            float uh = c0;
            uh = fmaf(fi[0], ra0, uh); uh = fmaf(fi[1], ra1, uh);
            uh = fmaf(fi[2], ra2, uh); uh = fmaf(fi[3], ra3, uh);
            uh = fmaf(fi[4], ra4, uh); uh = fmaf(fi[5], ra5, uh);
            #pragma unroll
            for (int j = 0; j < 6; ++j) {
                float vj;
                vj = fall[j*6+0] * rb0;
                vj = fmaf(fall[j*6+1], rb1, vj);
                vj = fmaf(fall[j*6+2], rb2, vj);
                vj = fmaf(fall[j*6+3], rb3, vj);
                vj = fmaf(fall[j*6+4], rb4, vj);
                vj = fmaf(fall[j*6+5], rb5, vj);
                float e = fmaxf(uh + vj, 0.0f);
                acc[j] = fmaf(e, w2, acc[j]);
            }
        }
        float b2 = W[O_MISC + 1];
        float* ao = adj_out + (size_t)b * 36 + n * 6;
        #pragma unroll
        for (int j = 0; j < 6; ++j) {
            float av = (j == n) ? 0.0f : sigmoidf_(acc[j] + b2);
            adj_s[s * 36 + n * 6 + j] = av;
            ao[j] = av;
        }
    }
    __syncthreads();

    if (active) {
        // ---- structured[n][i] = sum_j adj[i][j] * f[n][j] ----
        float adjv[36];
        #pragma unroll
        for (int q = 0; q < 9; ++q) {
            float4 v = *reinterpret_cast<const float4*>(&adj_s[s * 36 + q * 4]);
            adjv[q*4+0] = v.x; adjv[q*4+1] = v.y; adjv[q*4+2] = v.z; adjv[q*4+3] = v.w;
        }
        float st[6];
        #pragma unroll
        for (int i = 0; i < 6; ++i) {
            float v = 0.f;
            #pragma unroll
            for (int j = 0; j < 6; ++j) v = fmaf(adjv[i*6 + j], fi[j], v);
            st[i] = v;
        }

        // ---- h1 = relu(st @ Wd1 + bd1) ----
        float h1[32];
        #pragma unroll
        for (int o4 = 0; o4 < 8; ++o4) {
            float4 v = *reinterpret_cast<const float4*>(&W[O_BD1 + o4*4]);
            h1[o4*4+0] = v.x; h1[o4*4+1] = v.y; h1[o4*4+2] = v.z; h1[o4*4+3] = v.w;
        }
        #pragma unroll
        for (int m = 0; m < 6; ++m) {
            float sm = st[m];
            #pragma unroll
            for (int o4 = 0; o4 < 8; ++o4) {
                float4 w = *reinterpret_cast<const float4*>(&W[O_WD1 + m*32 + o4*4]);
                h1[o4*4+0] = fmaf(sm, w.x, h1[o4*4+0]);
                h1[o4*4+1] = fmaf(sm, w.y, h1[o4*4+1]);
                h1[o4*4+2] = fmaf(sm, w.z, h1[o4*4+2]);
                h1[o4*4+3] = fmaf(sm, w.w, h1[o4*4+3]);
            }
        }
        #pragma unroll
        for (int o = 0; o < 32; ++o) h1[o] = fmaxf(h1[o], 0.0f);

        // ---- h2 = relu(h1 @ Wd2 + bd2) ----
        float h2[32];
        #pragma unroll
        for (int o4 = 0; o4 < 8; ++o4) {
            float4 v = *reinterpret_cast<const float4*>(&W[O_BD2 + o4*4]);
            h2[o4*4+0] = v.x; h2[o4*4+1] = v.y; h2[o4*4+2] = v.z; h2[o4*4+3] = v.w;
        }
        #pragma unroll
        for (int k = 0; k < 32; ++k) {
            float hk = h1[k];
            #pragma unroll
            for (int o4 = 0; o4 < 8; ++o4) {
                float4 w = *reinterpret_cast<const float4*>(&W[O_WD2 + k*32 + o4*4]);
                h2[o4*4+0] = fmaf(hk, w.x, h2[o4*4+0]);
                h2[o4*4+1] = fmaf(hk, w.y, h2[o4*4+1]);
                h2[o4*4+2] = fmaf(hk, w.z, h2[o4*4+2]);
                h2[o4*4+3] = fmaf(hk, w.w, h2[o4*4+3]);
            }
        }
        #pragma unroll
        for (int o = 0; o < 32; ++o) h2[o] = fmaxf(h2[o], 0.0f);

        // ---- pred = h2 @ Wd3 + bd3 ----
        float pr[6];
        #pragma unroll
        for (int j = 0; j < 6; ++j) pr[j] = W[O_BD3 + j];
        #pragma unroll
        for (int k = 0; k < 32; ++k) {
            float hk = h2[k];
            #pragma unroll
            for (int j = 0; j < 6; ++j) pr[j] = fmaf(hk, W[O_WD3 + k*6 + j], pr[j]);
        }
        float* po = pred_out + (size_t)b * 36 + n * 6;
        #pragma unroll
        for (int j = 0; j < 6; ++j) po[j] = pr[j];

        float df[6];
        #pragma unroll
        for (int j = 0; j < 6; ++j) df[j] = fabsf(fi[j] - pr[j]);

        // ---- s1 = relu([fi,pr,df] @ Ws1 + bs1) ----
        float s1[32];
        #pragma unroll
        for (int o4 = 0; o4 < 8; ++o4) {
            float4 v = *reinterpret_cast<const float4*>(&W[O_BS1 + o4*4]);
            s1[o4*4+0] = v.x; s1[o4*4+1] = v.y; s1[o4*4+2] = v.z; s1[o4*4+3] = v.w;
        }
        #pragma unroll
        for (int m = 0; m < 6; ++m) {
            float a = fi[m], p = pr[m], d = df[m];
            #pragma unroll
            for (int o4 = 0; o4 < 8; ++o4) {
                float4 wa = *reinterpret_cast<const float4*>(&W[O_WS1 + m*32 + o4*4]);
                float4 wp = *reinterpret_cast<const float4*>(&W[O_WS1 + (6+m)*32 + o4*4]);
                float4 wd = *reinterpret_cast<const float4*>(&W[O_WS1 + (12+m)*32 + o4*4]);
                s1[o4*4+0] = fmaf(a, wa.x, fmaf(p, wp.x, fmaf(d, wd.x, s1[o4*4+0])));
                s1[o4*4+1] = fmaf(a, wa.y, fmaf(p, wp.y, fmaf(d, wd.y, s1[o4*4+1])));
                s1[o4*4+2] = fmaf(a, wa.z, fmaf(p, wp.z, fmaf(d, wd.z, s1[o4*4+2])));
                s1[o4*4+3] = fmaf(a, wa.w, fmaf(p, wp.w, fmaf(d, wd.w, s1[o4*4+3])));
            }
        }
        #pragma unroll
        for (int o = 0; o < 32; ++o) s1[o] = fmaxf(s1[o], 0.0f);

        // ---- s2 = relu(s1 @ Ws2 + bs2) ----
        float s2[16];
        #pragma unroll
        for (int o4 = 0; o4 < 4; ++o4) {
            float4 v = *reinterpret_cast<const float4*>(&W[O_BS2 + o4*4]);
            s2[o4*4+0] = v.x; s2[o4*4+1] = v.y; s2[o4*4+2] = v.z; s2[o4*4+3] = v.w;
        }
        #pragma unroll
        for (int k = 0; k < 32; ++k) {
            float sk = s1[k];
            #pragma unroll
            for (int o4 = 0; o4 < 4; ++o4) {
                float4 w = *reinterpret_cast<const float4*>(&W[O_WS2 + k*16 + o4*4]);
                s2[o4*4+0] = fmaf(sk, w.x, s2[o4*4+0]);
                s2[o4*4+1] = fmaf(sk, w.y, s2[o4*4+1]);
                s2[o4*4+2] = fmaf(sk, w.z, s2[o4*4+2]);
                s2[o4*4+3] = fmaf(sk, w.w, s2[o4*4+3]);
            }
        }
        #pragma unroll
        for (int o = 0; o < 16; ++o) s2[o] = fmaxf(s2[o], 0.0f);

        // ---- s3 = sigmoid(s2 @ Ws3 + bs3) ----
        float s3 = W[O_MISC];
        #pragma unroll
        for (int k4 = 0; k4 < 4; ++k4) {
            float4 w = *reinterpret_cast<const float4*>(&W[O_WS3 + k4*4]);
            s3 = fmaf(s2[k4*4+0], w.x, s3);
            s3 = fmaf(s2[k4*4+1], w.y, s3);
            s3 = fmaf(s2[k4*4+2], w.z, s3);
            s3 = fmaf(s2[k4*4+3], w.w, s3);
        }
        sc_s[s * 6 + n] = sigmoidf_(s3);
    }
    __syncthreads();

    if (active && n == 0) {
        float sum = sc_s[s*6+0] + sc_s[s*6+1] + sc_s[s*6+2]
                  + sc_s[s*6+3] + sc_s[s*6+4] + sc_s[s*6+5];
        scores[b] = sum * (1.0f / 6.0f);
    }
}

extern "C" void kernel_launch(void* const* d_in, const int* in_sizes, int n_in,
                              void* d_out, int out_size, void* d_ws, size_t ws_size,
                              hipStream_t stream) {
    const float* factors = (const float*)d_in[0];
    const float* Wn  = (const float*)d_in[1];
    const float* bn  = (const float*)d_in[2];
    const float* We1 = (const float*)d_in[3];
    const float* be1 = (const float*)d_in[4];
    const float* We2 = (const float*)d_in[5];
    const float* be2 = (const float*)d_in[6];
    const float* Wd1 = (const float*)d_in[7];
    const float* bd1 = (const float*)d_in[8];
    const float* Wd2 = (const float*)d_in[9];
    const float* bd2 = (const float*)d_in[10];
    const float* Wd3 = (const float*)d_in[11];
    const float* bd3 = (const float*)d_in[12];
    const float* Ws1 = (const float*)d_in[13];
    const float* bs1 = (const float*)d_in[14];
    const float* Ws2 = (const float*)d_in[15];
    const float* bs2 = (const float*)d_in[16];
    const float* Ws3 = (const float*)d_in[17];
    const float* bs3 = (const float*)d_in[18];

    int B = in_sizes[0] / 36;

    float* adj_out  = (float*)d_out;                       // [B,6,6]
    float* pred_out = (float*)d_out + (size_t)B * 36;      // [B,6,6]
    float* scores   = (float*)d_out + (size_t)B * 72;      // [B]
    float* rec      = (float*)d_ws;                        // 512 floats

    hipLaunchKernelGGL(fold_kernel, dim3(1), dim3(512), 0, stream,
                       Wn, bn, We1, be1, We2, rec);

    int nblocks = (B + SPB - 1) / SPB;
    hipLaunchKernelGGL(fused_kernel, dim3(nblocks), dim3(NT), 0, stream,
                       factors, rec,
                       Wd1, bd1, Wd2, bd2, Wd3, bd3,
                       Ws1, bs1, Ws2, bs2, Ws3, bs3, be2,
                       adj_out, pred_out, scores, B);
}